// Round 7
// baseline (166810.950 us; speedup 1.0000x reference)
//
#include <hip/hip_runtime.h>
#include <math.h>

// B=256 T=512 DIN=25 P=128 HID=256 3H=768 L=5 Q=0.15 EPS=1e-5
// Full-fp32. ws-tiered batch groups (Bg=128 expected => 2 groups), stable
// length-sort so groups are length-homogeneous; nch[g]=ceil(maxlen_g/64)
// computed on device so short groups finish in fewer rounds (bwd chunk index
// is nch-aware). Per (group,layer): 9 fused rounds; each launch = NR recur
// blocks (first; 512 thr, 4 samples, K split across thread halves, col-major
// float4 weight loads) + NG gemm blocks (128x128 tile) overlapping on the
// remaining CUs. launch_bounds(512,2) prevents the VGPR-36 spill seen in R5.

#define CH 64

// ---------------- stable sort + per-group chunk counts ----------------
__global__ __launch_bounds__(256)
void sort_k(const int* __restrict__ len, int* __restrict__ perm,
            int* __restrict__ nchp, int Bg)
{
    __shared__ int ll[256];
    __shared__ int lp[256];
    const int i = threadIdx.x;
    const int li = len[i];
    ll[i] = li;
    __syncthreads();
    int rk = 0;
    for (int j = 0; j < 256; j++) {
        int lj = ll[j];
        rk += (lj < li || (lj == li && j < i)) ? 1 : 0;
    }
    lp[rk] = i;
    __syncthreads();
    perm[i] = lp[i];
    const int ngrp = 256 / Bg;
    if (i < ngrp) {
        int mx = ll[lp[i * Bg + Bg - 1]];          // ascending sort -> last rank
        int nch = (mx + 63) >> 6;
        nchp[i] = nch < 1 ? 1 : (nch > 8 ? 8 : nch);
    }
}

// ---------------- Whh to column-major per gate: whhCM[l][d][g][j][k] --------
__global__ __launch_bounds__(256)
void prep_whhCM_k(const float* __restrict__ Whh0, const float* __restrict__ Whh,
                  float* __restrict__ out)
{
    int id = blockIdx.x * 256 + threadIdx.x;   // exactly 1,966,080 threads
    int u = id / 196608, rr = id % 196608;     // u = l*2+d
    int g = rr / 65536, r2 = rr % 65536;
    int j = r2 / 256, k = r2 % 256;
    int l = u >> 1, d = u & 1;
    int row = g * 256 + j;
    out[id] = (l == 0) ? Whh0[(size_t)(d * 768 + row) * 256 + k]
                       : Whh[(size_t)(((l - 1) * 2 + d) * 768 + row) * 256 + k];
}

// ---------------- input projection: LN -> FC(25->128) -> GELU -> FC(128->128) --
__global__ __launch_bounds__(128)
void input_proj_k(const float* __restrict__ x, const int* __restrict__ lengths,
                  const int* __restrict__ perm,
                  const float* __restrict__ lng, const float* __restrict__ lnb,
                  const float* __restrict__ w1, const float* __restrict__ b1v,
                  const float* __restrict__ w2, const float* __restrict__ b2v,
                  float* __restrict__ out, int g0)
{
    const int btl = blockIdx.x;                // group-local (sl*512 + t)
    const int sl  = btl >> 9;
    const int t   = btl & 511;
    const int b   = perm[g0 + sl];
    if (t >= lengths[b]) return;               // masked rows never read downstream
    const int tid = threadIdx.x;
    __shared__ float xs[25];
    __shared__ float xn[25];
    __shared__ float hs[128];
    if (tid < 25) xs[tid] = x[((size_t)b * 512 + t) * 25 + tid];
    __syncthreads();
    if (tid < 25) {
        float mu = 0.f;
        #pragma unroll
        for (int k = 0; k < 25; k++) mu += xs[k];
        mu *= (1.f / 25.f);
        float var = 0.f;
        #pragma unroll
        for (int k = 0; k < 25; k++) { float dd = xs[k] - mu; var += dd * dd; }
        var *= (1.f / 25.f);
        float rstd = 1.f / sqrtf(var + 1e-5f);
        xn[tid] = (xs[tid] - mu) * rstd * lng[tid] + lnb[tid];
    }
    __syncthreads();
    float a = b1v[tid];
    #pragma unroll
    for (int k = 0; k < 25; k++) a = fmaf(xn[k], w1[k * 128 + tid], a);
    float ge = 0.5f * a * (1.f + erff(a * 0.70710678118654752440f));
    hs[tid] = ge;
    __syncthreads();
    float o = b2v[tid];
    #pragma unroll 8
    for (int k = 0; k < 128; k++) o = fmaf(hs[k], w2[k * 128 + tid], o);
    out[(size_t)btl * 128 + tid] = o;
}

// ---------------- fused round: recur(chunk r-1) blocks first, gemm(chunk r) --
__global__ __launch_bounds__(512, 2)
void round_k(const float* __restrict__ A, int K,
             const float* __restrict__ W,      // raw Wih layer slice [2][768][K]
             const float* __restrict__ bi,     // [2][768]
             const int* __restrict__ lengths, const int* __restrict__ perm,
             const int* __restrict__ nchp, int gidx, int g0, int Bg,
             float* __restrict__ xw_w,         // gemm out (round r)
             const float* __restrict__ xw_r,   // recur in (round r-1)
             const float* __restrict__ whl,    // whhCM layer slice [2][3][256][256]
             const float* __restrict__ bhh,    // [2][768]
             float* __restrict__ Y,            // bout [Bg*512][512]
             float* __restrict__ hstate,       // [2*Bg][256]
             int NR, int r)
{
    __shared__ float As[8][132];       // gemm A stage [k][m]
    __shared__ float Bs[8][132];       // gemm B stage [k][n]
    __shared__ float h_s[2][256][4];   // recur double-buffered h [k][sample]
    __shared__ float ps[12][260];      // recur K-half partials [g*4+s][j]

    const int tid = threadIdx.x;
    const int nch = nchp[gidx];

    if ((int)blockIdx.x < NR) {
        // ================= recur role (4 samples, one dir, K split 2-way) ====
        if (r == 0) return;
        const int half = NR >> 1;
        const int d    = ((int)blockIdx.x >= half) ? 1 : 0;
        const int tile = (int)blockIdx.x - d * half;
        const int b0   = tile * 4;
        const int lo   = d ? (nch - r) * 64 : (r - 1) * 64;
        if (lo < 0 || lo >= 512) return;
        const int first = (r == 1);

        int nst[4];
        int nmax = 0;
        #pragma unroll
        for (int s = 0; s < 4; s++) {
            int L = lengths[perm[g0 + b0 + s]];
            int n = min(lo + CH, L) - lo;
            nst[s] = (n < 0) ? 0 : n;
            nmax = max(nmax, nst[s]);
        }
        if (!first && nmax <= 0) return;       // hstate already valid

        const int kh = tid >> 8;               // K half 0/1
        const int j  = tid & 255;              // hidden unit
        float* hg = hstate + (size_t)(d * Bg + b0) * 256;
        if (kh == 0) {
            #pragma unroll
            for (int s = 0; s < 4; s++)
                h_s[0][j][s] = first ? 0.f : hg[s * 256 + j];
        }
        __syncthreads();

        const float* wR = whl + ((size_t)(d * 3 + 0)) * 65536 + j * 256 + kh * 128;
        const float* wZ = wR + 65536;
        const float* wN = wZ + 65536;
        const float* xwd = xw_r + (size_t)(d * Bg + b0) * (64 * 768);
        const float bhr = bhh[d * 768 + j];
        const float bhz = bhh[d * 768 + 256 + j];
        const float bhn = bhh[d * 768 + 512 + j];

        int par = 0;
        for (int st = 0; st < nmax; st++) {
            float ar[4] = {}, az[4] = {}, an[4] = {};
            #pragma unroll 4
            for (int k4 = 0; k4 < 32; k4++) {
                float4 wr = *(const float4*)(wR + k4 * 4);
                float4 wz = *(const float4*)(wZ + k4 * 4);
                float4 wn = *(const float4*)(wN + k4 * 4);
                const int kb = kh * 128 + k4 * 4;
                float4 h0 = *(const float4*)&h_s[par][kb + 0][0];
                float4 h1 = *(const float4*)&h_s[par][kb + 1][0];
                float4 h2 = *(const float4*)&h_s[par][kb + 2][0];
                float4 h3 = *(const float4*)&h_s[par][kb + 3][0];
                ar[0] = fmaf(h0.x, wr.x, ar[0]); ar[1] = fmaf(h0.y, wr.x, ar[1]);
                ar[2] = fmaf(h0.z, wr.x, ar[2]); ar[3] = fmaf(h0.w, wr.x, ar[3]);
                az[0] = fmaf(h0.x, wz.x, az[0]); az[1] = fmaf(h0.y, wz.x, az[1]);
                az[2] = fmaf(h0.z, wz.x, az[2]); az[3] = fmaf(h0.w, wz.x, az[3]);
                an[0] = fmaf(h0.x, wn.x, an[0]); an[1] = fmaf(h0.y, wn.x, an[1]);
                an[2] = fmaf(h0.z, wn.x, an[2]); an[3] = fmaf(h0.w, wn.x, an[3]);
                ar[0] = fmaf(h1.x, wr.y, ar[0]); ar[1] = fmaf(h1.y, wr.y, ar[1]);
                ar[2] = fmaf(h1.z, wr.y, ar[2]); ar[3] = fmaf(h1.w, wr.y, ar[3]);
                az[0] = fmaf(h1.x, wz.y, az[0]); az[1] = fmaf(h1.y, wz.y, az[1]);
                az[2] = fmaf(h1.z, wz.y, az[2]); az[3] = fmaf(h1.w, wz.y, az[3]);
                an[0] = fmaf(h1.x, wn.y, an[0]); an[1] = fmaf(h1.y, wn.y, an[1]);
                an[2] = fmaf(h1.z, wn.y, an[2]); an[3] = fmaf(h1.w, wn.y, an[3]);
                ar[0] = fmaf(h2.x, wr.z, ar[0]); ar[1] = fmaf(h2.y, wr.z, ar[1]);
                ar[2] = fmaf(h2.z, wr.z, ar[2]); ar[3] = fmaf(h2.w, wr.z, ar[3]);
                az[0] = fmaf(h2.x, wz.z, az[0]); az[1] = fmaf(h2.y, wz.z, az[1]);
                az[2] = fmaf(h2.z, wz.z, az[2]); az[3] = fmaf(h2.w, wz.z, az[3]);
                an[0] = fmaf(h2.x, wn.z, an[0]); an[1] = fmaf(h2.y, wn.z, an[1]);
                an[2] = fmaf(h2.z, wn.z, an[2]); an[3] = fmaf(h2.w, wn.z, an[3]);
                ar[0] = fmaf(h3.x, wr.w, ar[0]); ar[1] = fmaf(h3.y, wr.w, ar[1]);
                ar[2] = fmaf(h3.z, wr.w, ar[2]); ar[3] = fmaf(h3.w, wr.w, ar[3]);
                az[0] = fmaf(h3.x, wz.w, az[0]); az[1] = fmaf(h3.y, wz.w, az[1]);
                az[2] = fmaf(h3.z, wz.w, az[2]); az[3] = fmaf(h3.w, wz.w, az[3]);
                an[0] = fmaf(h3.x, wn.w, an[0]); an[1] = fmaf(h3.y, wn.w, an[1]);
                an[2] = fmaf(h3.z, wn.w, an[2]); an[3] = fmaf(h3.w, wn.w, an[3]);
            }
            if (kh == 1) {
                #pragma unroll
                for (int s = 0; s < 4; s++) {
                    ps[s][j]     = ar[s];
                    ps[4 + s][j] = az[s];
                    ps[8 + s][j] = an[s];
                }
            }
            __syncthreads();
            if (kh == 0) {
                float hnew[4];
                #pragma unroll
                for (int s = 0; s < 4; s++) {
                    float hv = h_s[par][j][s];
                    float hn = hv;
                    if (st < nst[s]) {
                        int p = d ? (lo + nst[s] - 1 - st) : (lo + st);
                        const float* xr = xwd + ((size_t)s * 64 + (p - lo)) * 768;
                        float gr = ar[s] + ps[s][j] + bhr;
                        float gz = az[s] + ps[4 + s][j] + bhz;
                        float gn = an[s] + ps[8 + s][j] + bhn;
                        float rg = 1.f / (1.f + expf(-(xr[j] + gr)));
                        float zg = 1.f / (1.f + expf(-(xr[256 + j] + gz)));
                        float ng = tanhf(xr[512 + j] + rg * gn);
                        hn = (1.f - zg) * ng + zg * hv;
                        Y[((size_t)((b0 + s) * 512 + p)) * 512 + d * 256 + j] = hn;
                    }
                    hnew[s] = hn;
                }
                *(float4*)&h_s[par ^ 1][j][0] =
                    make_float4(hnew[0], hnew[1], hnew[2], hnew[3]);
            }
            par ^= 1;
            __syncthreads();
        }
        if (kh == 0) {
            #pragma unroll
            for (int s = 0; s < 4; s++) hg[s * 256 + j] = h_s[par][j][s];
        }
    } else {
        // ================= gemm role (128x128 tile, 2 samples) ===============
        const int gid  = blockIdx.x - NR;
        const int nt   = gid % 6;
        const int rest = gid / 6;
        const int half = Bg >> 1;
        const int dir  = (rest >= half) ? 1 : 0;
        const int pr   = rest - dir * half;
        const int s0   = pr * 2;
        const int lo   = dir ? (nch - 1 - r) * 64 : r * 64;
        if (lo < 0 || lo >= 512) return;
        const int l0v = lengths[perm[g0 + s0]];
        const int l1v = lengths[perm[g0 + s0 + 1]];
        if (l0v <= lo && l1v <= lo) return;

        float acc[4][8] = {};
        const int tr = tid >> 4;               // 0..31 -> rows tr*4..+3
        const int tc = tid & 15;               // cols {tc*4..+3, 64+tc*4..+3}
        const int arw = tid >> 2, ak = (tid & 3) * 2;   // A stage: 128 rows x f2
        const int bn  = tid >> 2, bk = (tid & 3) * 2;   // B stage: 128 cols x f2

        const int aslot = s0 + (arw >> 6);
        const float* Ap = A + (size_t)(aslot * 512 + lo + (arw & 63)) * K + ak;
        const float* Wp = W + ((size_t)dir * 768 + nt * 128 + bn) * K + bk;

        for (int k0 = 0; k0 < K; k0 += 8) {
            float2 av = *(const float2*)(Ap + k0);
            float2 bv = *(const float2*)(Wp + k0);
            __syncthreads();
            As[ak][arw] = av.x; As[ak + 1][arw] = av.y;
            Bs[bk][bn]  = bv.x; Bs[bk + 1][bn]  = bv.y;
            __syncthreads();
            #pragma unroll
            for (int kk = 0; kk < 8; kk++) {
                float4 a4 = *(const float4*)&As[kk][tr * 4];
                float4 b0 = *(const float4*)&Bs[kk][tc * 4];
                float4 b1 = *(const float4*)&Bs[kk][64 + tc * 4];
                float ax[4] = {a4.x, a4.y, a4.z, a4.w};
                float bx[8] = {b0.x, b0.y, b0.z, b0.w, b1.x, b1.y, b1.z, b1.w};
                #pragma unroll
                for (int i = 0; i < 4; i++)
                    #pragma unroll
                    for (int jj = 0; jj < 8; jj++)
                        acc[i][jj] = fmaf(ax[i], bx[jj], acc[i][jj]);
            }
        }
        const int cb = dir * 768 + nt * 128;
        float bv0[4], bv1[4];
        #pragma unroll
        for (int jj = 0; jj < 4; jj++) {
            bv0[jj] = bi[cb + tc * 4 + jj];
            bv1[jj] = bi[cb + 64 + tc * 4 + jj];
        }
        #pragma unroll
        for (int i = 0; i < 4; i++) {
            const int row  = tr * 4 + i;
            const int slot = s0 + (row >> 6);
            float* o = xw_w + (size_t)((dir * Bg + slot) * 64 + (row & 63)) * 768
                     + nt * 128 + tc * 4;
            float4 c0 = make_float4(acc[i][0] + bv0[0], acc[i][1] + bv0[1],
                                    acc[i][2] + bv0[2], acc[i][3] + bv0[3]);
            float4 c1 = make_float4(acc[i][4] + bv1[0], acc[i][5] + bv1[1],
                                    acc[i][6] + bv1[2], acc[i][7] + bv1[3]);
            *(float4*)(o)      = c0;
            *(float4*)(o + 64) = c1;
        }
    }
}

// ---------------- top-Q pooling + classifier head ----------------
__global__ __launch_bounds__(256)
void pool_k(const float* __restrict__ H, const int* __restrict__ lengths,
            const int* __restrict__ perm,
            const float* __restrict__ Wc, const float* __restrict__ bcp,
            float* __restrict__ out, int g0)
{
    const int bl = blockIdx.x;
    const int b  = perm[g0 + bl];
    const int tid = threadIdx.x;
    __shared__ float sc[512];
    __shared__ int   sel[128];
    __shared__ int   nsel;
    __shared__ float red[256];
    const int len = lengths[b];
    const int k = max(1, (int)ceilf((float)len * 0.15f));   // jnp fp32 semantics
    if (tid == 0) nsel = 0;
    for (int t = tid; t < 512; t += 256) {
        float s;
        if (t < len) {
            const float* row = H + ((size_t)bl * 512 + t) * 512;
            float acc = 0.f;
            for (int j = 0; j < 512; j++) acc = fmaf(row[j], row[j], acc);
            s = sqrtf(acc);
        } else s = -1e9f;
        sc[t] = s;
    }
    __syncthreads();
    for (int t = tid; t < 512; t += 256) {
        if (t < len) {
            const float s = sc[t];
            int cnt = 0;
            for (int u = 0; u < 512; u++) {
                float su = sc[u];
                cnt += (su > s || (su == s && u < t)) ? 1 : 0;
            }
            if (cnt < k) { int p = atomicAdd(&nsel, 1); sel[p] = t; }
        }
    }
    __syncthreads();
    const int ns = nsel;                       // == k
    float part = 0.f;
    for (int j = tid; j < 512; j += 256) {
        float acc = 0.f;
        for (int i = 0; i < ns; i++)
            acc += H[((size_t)bl * 512 + sel[i]) * 512 + j];
        part += (acc / (float)k) * Wc[j];
    }
    red[tid] = part;
    __syncthreads();
    for (int s2 = 128; s2 > 0; s2 >>= 1) {
        if (tid < s2) red[tid] += red[tid + s2];
        __syncthreads();
    }
    if (tid == 0) out[b] = red[0] + bcp[0];
}

// ---------------- host ----------------
static inline size_t alup(size_t x) { return (x + 255) & ~255ull; }

static size_t tier_bytes(int Bg)
{
    return 2 * alup((size_t)Bg * 512 * 512 * 4)        // H ping-pong
         + 2 * alup((size_t)Bg * 2 * 64 * 768 * 4)     // xw ping-pong
         + alup(1966080ull * 4)                        // whhCM
         + alup((size_t)Bg * 2 * 256 * 4)              // hstate
         + alup(2048);                                 // perm + nch
}

extern "C" void kernel_launch(void* const* d_in, const int* in_sizes, int n_in,
                              void* d_out, int out_size, void* d_ws, size_t ws_size,
                              hipStream_t stream)
{
    const float* x    = (const float*)d_in[0];
    const int*   len  = (const int*)  d_in[1];
    const float* ln_g = (const float*)d_in[2];
    const float* ln_b = (const float*)d_in[3];
    const float* w1   = (const float*)d_in[4];
    const float* b1   = (const float*)d_in[5];
    const float* w2   = (const float*)d_in[6];
    const float* b2   = (const float*)d_in[7];
    const float* Wih0 = (const float*)d_in[8];
    const float* Whh0 = (const float*)d_in[9];
    const float* bih0 = (const float*)d_in[10];
    const float* bhh0 = (const float*)d_in[11];
    const float* Wih  = (const float*)d_in[12];
    const float* Whh  = (const float*)d_in[13];
    const float* bih  = (const float*)d_in[14];
    const float* bhh  = (const float*)d_in[15];
    const float* Wc   = (const float*)d_in[16];
    const float* bc   = (const float*)d_in[17];
    float* out = (float*)d_out;

    int Bg = 0;
    const int tiers[5] = {128, 64, 32, 16, 8};
    for (int i = 0; i < 5; i++)
        if (ws_size >= tier_bytes(tiers[i])) { Bg = tiers[i]; break; }
    if (Bg == 0) return;

    char* ws = (char*)d_ws;
    size_t off = 0;
    auto alloc = [&](size_t bytes) { size_t o = off; off += alup(bytes); return o; };
    float* h0    = (float*)(ws + alloc((size_t)Bg * 512 * 512 * 4));
    float* h1    = (float*)(ws + alloc((size_t)Bg * 512 * 512 * 4));
    float* xwA   = (float*)(ws + alloc((size_t)Bg * 2 * 64 * 768 * 4));
    float* xwB   = (float*)(ws + alloc((size_t)Bg * 2 * 64 * 768 * 4));
    float* whhCM = (float*)(ws + alloc(1966080ull * 4));
    float* hst   = (float*)(ws + alloc((size_t)Bg * 2 * 256 * 4));
    int*   perm  = (int*)  (ws + alloc(2048));
    int*   nchp  = perm + 256;
    float* xwbuf[2] = {xwA, xwB};

    sort_k<<<1, 256, 0, stream>>>(len, perm, nchp, Bg);
    prep_whhCM_k<<<7680, 256, 0, stream>>>(Whh0, Whh, whhCM);

    const int NR = Bg / 2;                 // recur blocks (2 dirs x Bg/4 tiles)
    const int NG = 6 * Bg;                 // gemm blocks (6 cols x Bg/2 pairs x 2)

    for (int g0 = 0; g0 < 256; g0 += Bg) {
        const int gidx = g0 / Bg;
        input_proj_k<<<Bg * 512, 128, 0, stream>>>(x, len, perm, ln_g, ln_b,
                                                   w1, b1, w2, b2, h0, g0);
        float* bin = h0;
        float* bout = h1;
        for (int l = 0; l < 5; l++) {
            const int K = (l == 0) ? 128 : 512;
            const float* Wl  = (l == 0) ? Wih0 : (Wih + (size_t)(l - 1) * 2 * 768 * 512);
            const float* bil = (l == 0) ? bih0 : (bih + (size_t)(l - 1) * 1536);
            const float* whl = whhCM + (size_t)l * 393216;
            const float* bhl = (l == 0) ? bhh0 : (bhh + (size_t)(l - 1) * 1536);
            for (int r = 0; r <= 8; r++) {
                round_k<<<NR + NG, 512, 0, stream>>>(
                    bin, K, Wl, bil, len, perm, nchp, gidx, g0, Bg,
                    xwbuf[r & 1], xwbuf[(r & 1) ^ 1],
                    whl, bhl, bout, hst, NR, r);
            }
            float* tmp = bin; bin = bout; bout = tmp;
        }
        pool_k<<<Bg, 256, 0, stream>>>(bin, len, perm, Wc, bc, out, g0);
    }
}

// Round 8
// 49201.508 us; speedup vs baseline: 3.3904x; 3.3904x over previous
//
#include <hip/hip_runtime.h>
#include <math.h>

// B=256 T=512 DIN=25 P=128 HID=256 3H=768 L=5 Q=0.15 EPS=1e-5
// Full-fp32. R4's proven fused round_k (52 VGPR, 19968B LDS, ~450us/round)
// with exactly three fixes: recur blocks first in the grid (R4 had them last,
// serializing behind 1536 gemm blocks), stable length-sort, and per-group
// nch=ceil(maxlen/64) so short groups skip rounds. Recurrence is per-CU
// L2-port bound (768KB Whh stream per block-step ~ 5.7us floor); R4's
// kq-split float4 weight loads are the only shape measured to approach it.

#define CH 64

// ---------------- stable sort + per-group chunk counts ----------------
__global__ __launch_bounds__(256)
void sort_k(const int* __restrict__ len, int* __restrict__ perm,
            int* __restrict__ nchp, int Bg)
{
    __shared__ int ll[256];
    __shared__ int lp[256];
    const int i = threadIdx.x;
    const int li = len[i];
    ll[i] = li;
    __syncthreads();
    int rk = 0;
    for (int j = 0; j < 256; j++) {
        int lj = ll[j];
        rk += (lj < li || (lj == li && j < i)) ? 1 : 0;
    }
    lp[rk] = i;
    __syncthreads();
    perm[i] = lp[i];
    const int ngrp = 256 / Bg;
    if (i < ngrp) {
        int mx = ll[lp[i * Bg + Bg - 1]];      // ascending -> last rank is max
        int nch = (mx + 63) >> 6;
        nchp[i] = nch < 1 ? 1 : (nch > 8 ? 8 : nch);
    }
}

// ---------------- Whh transpose: whhT[l][d][k][c] ----------------
__global__ __launch_bounds__(256)
void prep_whhT_k(const float* __restrict__ Whh0, const float* __restrict__ Whh,
                 float* __restrict__ out)
{
    int id = blockIdx.x * 256 + threadIdx.x;   // exactly 1,966,080 threads
    int u = id / 196608, rr = id % 196608;     // u = l*2+d
    int k = rr / 768, c = rr % 768;
    int l = u >> 1, d = u & 1;
    out[id] = (l == 0) ? Whh0[(size_t)(d * 768 + c) * 256 + k]
                       : Whh[(size_t)(((l - 1) * 2 + d) * 768 + c) * 256 + k];
}

// ---------------- input projection: LN -> FC(25->128) -> GELU -> FC(128->128) --
__global__ __launch_bounds__(128)
void input_proj_k(const float* __restrict__ x, const int* __restrict__ lengths,
                  const int* __restrict__ perm,
                  const float* __restrict__ lng, const float* __restrict__ lnb,
                  const float* __restrict__ w1, const float* __restrict__ b1v,
                  const float* __restrict__ w2, const float* __restrict__ b2v,
                  float* __restrict__ out, int g0)
{
    const int btl = blockIdx.x;                // group-local (sl*512 + t)
    const int sl  = btl >> 9;
    const int t   = btl & 511;
    const int b   = perm[g0 + sl];
    if (t >= lengths[b]) return;               // masked rows never read downstream
    const int tid = threadIdx.x;
    __shared__ float xs[25];
    __shared__ float xn[25];
    __shared__ float hs[128];
    if (tid < 25) xs[tid] = x[((size_t)b * 512 + t) * 25 + tid];
    __syncthreads();
    if (tid < 25) {
        float mu = 0.f;
        #pragma unroll
        for (int k = 0; k < 25; k++) mu += xs[k];
        mu *= (1.f / 25.f);
        float var = 0.f;
        #pragma unroll
        for (int k = 0; k < 25; k++) { float dd = xs[k] - mu; var += dd * dd; }
        var *= (1.f / 25.f);
        float rstd = 1.f / sqrtf(var + 1e-5f);
        xn[tid] = (xs[tid] - mu) * rstd * lng[tid] + lnb[tid];
    }
    __syncthreads();
    float a = b1v[tid];
    #pragma unroll
    for (int k = 0; k < 25; k++) a = fmaf(xn[k], w1[k * 128 + tid], a);
    float ge = 0.5f * a * (1.f + erff(a * 0.70710678118654752440f));
    hs[tid] = ge;
    __syncthreads();
    float o = b2v[tid];
    #pragma unroll 8
    for (int k = 0; k < 128; k++) o = fmaf(hs[k], w2[k * 128 + tid], o);
    out[(size_t)btl * 128 + tid] = o;
}

// ---------------- fused round: recur(chunk r-1) blocks FIRST, gemm(chunk r) --
// blocks [0, NR): recur role, NR = 2*Bg. One (sample s, dir d) per block,
//   256 thr, K split in quarters (kq) with float4 weight loads (the measured
//   ~7us/step shape), gs partial exchange, 2 syncs/step.
// blocks [NR, NR+12*Bg): GEMM role. 64Mx128N tile, A = H_l rows (stride K),
//   B = raw Wih slice [2][768][K] staged via LDS.
__global__ __launch_bounds__(256)
void round_k(const float* __restrict__ A, int K,
             const float* __restrict__ W,      // raw Wih layer slice [2][768][K]
             const float* __restrict__ bi,     // [2][768]
             const int* __restrict__ lengths, const int* __restrict__ perm,
             const int* __restrict__ nchp, int gidx, int g0, int Bg,
             float* __restrict__ xw_w,         // gemm out (round r)
             const float* __restrict__ xw_r,   // recur in (round r-1)
             const float* __restrict__ whhT,   // layer slice [2][256][768]
             const float* __restrict__ bhh,    // [2][768]
             float* __restrict__ Y,            // bout [Bg*512][512]
             float* __restrict__ hstate,       // [2*Bg][256]
             int NR, int r)
{
    __shared__ float As[8][68];        // gemm: [k][m]
    __shared__ float Bs[8][132];       // gemm: [k][n]
    __shared__ float h_s[260];         // recur: h state
    __shared__ float gs[4][776];       // recur: K-split partial gh

    const int tid = threadIdx.x;
    const int nch = nchp[gidx];

    if ((int)blockIdx.x < NR) {
        // ================= recur role =================
        if (r == 0) return;
        const int d   = ((int)blockIdx.x >= Bg) ? 1 : 0;
        const int s   = (int)blockIdx.x - d * Bg;
        const int lo  = d ? (nch - r) * 64 : (r - 1) * 64;
        if (lo < 0 || lo >= 512) return;
        const int len = lengths[perm[g0 + s]];
        int nst = min(lo + CH, len) - lo;
        if (nst < 0) nst = 0;
        const int first = (r == 1);
        if (!first && nst <= 0) return;        // hstate already valid

        float* hg = hstate + (size_t)(d * Bg + s) * 256;
        h_s[tid] = first ? 0.f : hg[tid];
        __syncthreads();

        const int kq  = tid >> 6;              // K quarter 0..3
        const int q4  = (tid & 63) * 4;        // col-4 base within gate
        const float* Wd  = whhT + (size_t)d * 196608;
        const float* xwd = xw_r + (size_t)(d * Bg + s) * 64 * 768;
        const float bh0 = bhh[d * 768 + tid];
        const float bh1 = bhh[d * 768 + 256 + tid];
        const float bh2 = bhh[d * 768 + 512 + tid];

        for (int st = 0; st < nst; st++) {
            const int p = d ? (lo + nst - 1 - st) : (lo + st);
            // phase 1: partial gh over this thread's K quarter, 12 cols
            float a0[4] = {}, a1[4] = {}, a2[4] = {};
            const float* wk = Wd + (size_t)(kq * 64) * 768 + q4;
            #pragma unroll 4
            for (int k4 = 0; k4 < 16; k4++) {
                float4 h4 = *(const float4*)&h_s[kq * 64 + k4 * 4];
                const float* w0 = wk + (size_t)(k4 * 4) * 768;
                float hk[4] = {h4.x, h4.y, h4.z, h4.w};
                #pragma unroll
                for (int kk = 0; kk < 4; kk++) {
                    const float* wr = w0 + (size_t)kk * 768;
                    float4 wv0 = *(const float4*)(wr);
                    float4 wv1 = *(const float4*)(wr + 256);
                    float4 wv2 = *(const float4*)(wr + 512);
                    float h = hk[kk];
                    a0[0] = fmaf(h, wv0.x, a0[0]); a0[1] = fmaf(h, wv0.y, a0[1]);
                    a0[2] = fmaf(h, wv0.z, a0[2]); a0[3] = fmaf(h, wv0.w, a0[3]);
                    a1[0] = fmaf(h, wv1.x, a1[0]); a1[1] = fmaf(h, wv1.y, a1[1]);
                    a1[2] = fmaf(h, wv1.z, a1[2]); a1[3] = fmaf(h, wv1.w, a1[3]);
                    a2[0] = fmaf(h, wv2.x, a2[0]); a2[1] = fmaf(h, wv2.y, a2[1]);
                    a2[2] = fmaf(h, wv2.z, a2[2]); a2[3] = fmaf(h, wv2.w, a2[3]);
                }
            }
            *(float4*)&gs[kq][q4]       = make_float4(a0[0], a0[1], a0[2], a0[3]);
            *(float4*)&gs[kq][256 + q4] = make_float4(a1[0], a1[1], a1[2], a1[3]);
            *(float4*)&gs[kq][512 + q4] = make_float4(a2[0], a2[1], a2[2], a2[3]);
            __syncthreads();
            // phase 2: gate update for h-dim j = tid
            float gr = bh0 + gs[0][tid] + gs[1][tid] + gs[2][tid] + gs[3][tid];
            float gz = bh1 + gs[0][256 + tid] + gs[1][256 + tid]
                           + gs[2][256 + tid] + gs[3][256 + tid];
            float gn = bh2 + gs[0][512 + tid] + gs[1][512 + tid]
                           + gs[2][512 + tid] + gs[3][512 + tid];
            const float* xr = xwd + (size_t)(p - lo) * 768;
            float rg = 1.f / (1.f + expf(-(xr[tid] + gr)));
            float zg = 1.f / (1.f + expf(-(xr[256 + tid] + gz)));
            float ng = tanhf(xr[512 + tid] + rg * gn);
            float hv = h_s[tid];
            float hn = (1.f - zg) * ng + zg * hv;
            h_s[tid] = hn;
            Y[((size_t)(s * 512 + p)) * 512 + d * 256 + tid] = hn;
            __syncthreads();
        }
        hg[tid] = h_s[tid];
    } else {
        // ================= GEMM role =================
        const int gid  = blockIdx.x - NR;
        const int nt   = gid % 6;
        const int rest = gid / 6;
        const int d    = (rest >= Bg) ? 1 : 0;
        const int s    = rest - d * Bg;
        const int lo   = d ? (nch - 1 - r) * 64 : r * 64;
        if (lo < 0 || lo >= 512) return;
        if (lengths[perm[g0 + s]] <= lo) return;   // chunk fully masked

        float acc[4][8] = {};
        const int tm = tid >> 4;                 // rows tm*4..+3
        const int tn = tid & 15;                 // cols {tn*4..+3, 64+tn*4..+3}
        const int arr = tid >> 2, ak = (tid & 3) * 2;
        const int bn = tid >> 1, bk = (tid & 1) * 4;

        const float* Ap = A + (size_t)(s * 512 + lo + arr) * K + ak;
        const float* Wp = W + ((size_t)d * 768 + nt * 128 + bn) * K + bk;

        for (int k0 = 0; k0 < K; k0 += 8) {
            float2 av = *(const float2*)(Ap + k0);
            float4 bv = *(const float4*)(Wp + k0);
            __syncthreads();
            As[ak][arr] = av.x; As[ak + 1][arr] = av.y;
            Bs[bk + 0][bn] = bv.x; Bs[bk + 1][bn] = bv.y;
            Bs[bk + 2][bn] = bv.z; Bs[bk + 3][bn] = bv.w;
            __syncthreads();
            #pragma unroll
            for (int kk = 0; kk < 8; kk++) {
                float4 a4 = *(const float4*)&As[kk][tm * 4];
                float4 b0v = *(const float4*)&Bs[kk][tn * 4];
                float4 b1v = *(const float4*)&Bs[kk][64 + tn * 4];
                float ar4[4] = {a4.x, a4.y, a4.z, a4.w};
                float br[8] = {b0v.x, b0v.y, b0v.z, b0v.w,
                               b1v.x, b1v.y, b1v.z, b1v.w};
                #pragma unroll
                for (int i = 0; i < 4; i++)
                    #pragma unroll
                    for (int j = 0; j < 8; j++)
                        acc[i][j] = fmaf(ar4[i], br[j], acc[i][j]);
            }
        }
        const int cb = d * 768 + nt * 128;
        float bv0[4], bv1[4];
        #pragma unroll
        for (int j = 0; j < 4; j++) {
            bv0[j] = bi[cb + tn * 4 + j];
            bv1[j] = bi[cb + 64 + tn * 4 + j];
        }
        #pragma unroll
        for (int i = 0; i < 4; i++) {
            const int row = tm * 4 + i;
            float* o = xw_w + (size_t)((d * Bg + s) * 64 + row) * 768 + nt * 128 + tn * 4;
            float4 c0 = make_float4(acc[i][0] + bv0[0], acc[i][1] + bv0[1],
                                    acc[i][2] + bv0[2], acc[i][3] + bv0[3]);
            float4 c1 = make_float4(acc[i][4] + bv1[0], acc[i][5] + bv1[1],
                                    acc[i][6] + bv1[2], acc[i][7] + bv1[3]);
            *(float4*)(o)      = c0;
            *(float4*)(o + 64) = c1;
        }
    }
}

// ---------------- top-Q pooling + classifier head ----------------
__global__ __launch_bounds__(256)
void pool_k(const float* __restrict__ H, const int* __restrict__ lengths,
            const int* __restrict__ perm,
            const float* __restrict__ Wc, const float* __restrict__ bcp,
            float* __restrict__ out, int g0)
{
    const int bl = blockIdx.x;
    const int b  = perm[g0 + bl];
    const int tid = threadIdx.x;
    __shared__ float sc[512];
    __shared__ int   sel[128];
    __shared__ int   nsel;
    __shared__ float red[256];
    const int len = lengths[b];
    const int k = max(1, (int)ceilf((float)len * 0.15f));   // jnp fp32 semantics
    if (tid == 0) nsel = 0;
    for (int t = tid; t < 512; t += 256) {
        float s;
        if (t < len) {
            const float* row = H + ((size_t)bl * 512 + t) * 512;
            float acc = 0.f;
            for (int j = 0; j < 512; j++) acc = fmaf(row[j], row[j], acc);
            s = sqrtf(acc);
        } else s = -1e9f;
        sc[t] = s;
    }
    __syncthreads();
    // stable top-k: include t iff (#strictly greater) + (#equal, smaller idx) < k
    for (int t = tid; t < 512; t += 256) {
        if (t < len) {
            const float s = sc[t];
            int cnt = 0;
            for (int u = 0; u < 512; u++) {
                float su = sc[u];
                cnt += (su > s || (su == s && u < t)) ? 1 : 0;
            }
            if (cnt < k) { int p = atomicAdd(&nsel, 1); sel[p] = t; }
        }
    }
    __syncthreads();
    const int ns = nsel;                       // == k
    float part = 0.f;
    for (int j = tid; j < 512; j += 256) {
        float acc = 0.f;
        for (int i = 0; i < ns; i++)
            acc += H[((size_t)bl * 512 + sel[i]) * 512 + j];
        part += (acc / (float)k) * Wc[j];
    }
    red[tid] = part;
    __syncthreads();
    for (int s2 = 128; s2 > 0; s2 >>= 1) {
        if (tid < s2) red[tid] += red[tid + s2];
        __syncthreads();
    }
    if (tid == 0) out[b] = red[0] + bcp[0];
}

// ---------------- host ----------------
static inline size_t alup(size_t x) { return (x + 255) & ~255ull; }

static size_t tier_bytes(int Bg)
{
    return 2 * alup((size_t)Bg * 512 * 512 * 4)        // H ping-pong
         + 2 * alup((size_t)Bg * 2 * 64 * 768 * 4)     // xw ping-pong
         + alup(1966080ull * 4)                        // whhT
         + alup((size_t)Bg * 2 * 256 * 4)              // hstate
         + alup(2048);                                 // perm + nch
}

extern "C" void kernel_launch(void* const* d_in, const int* in_sizes, int n_in,
                              void* d_out, int out_size, void* d_ws, size_t ws_size,
                              hipStream_t stream)
{
    const float* x    = (const float*)d_in[0];
    const int*   len  = (const int*)  d_in[1];
    const float* ln_g = (const float*)d_in[2];
    const float* ln_b = (const float*)d_in[3];
    const float* w1   = (const float*)d_in[4];
    const float* b1   = (const float*)d_in[5];
    const float* w2   = (const float*)d_in[6];
    const float* b2   = (const float*)d_in[7];
    const float* Wih0 = (const float*)d_in[8];
    const float* Whh0 = (const float*)d_in[9];
    const float* bih0 = (const float*)d_in[10];
    const float* bhh0 = (const float*)d_in[11];
    const float* Wih  = (const float*)d_in[12];
    const float* Whh  = (const float*)d_in[13];
    const float* bih  = (const float*)d_in[14];
    const float* bhh  = (const float*)d_in[15];
    const float* Wc   = (const float*)d_in[16];
    const float* bc   = (const float*)d_in[17];
    float* out = (float*)d_out;

    int Bg = 0;
    const int tiers[5] = {128, 64, 32, 16, 8};
    for (int i = 0; i < 5; i++)
        if (ws_size >= tier_bytes(tiers[i])) { Bg = tiers[i]; break; }
    if (Bg == 0) return;

    char* ws = (char*)d_ws;
    size_t off = 0;
    auto alloc = [&](size_t bytes) { size_t o = off; off += alup(bytes); return o; };
    float* h0    = (float*)(ws + alloc((size_t)Bg * 512 * 512 * 4));
    float* h1    = (float*)(ws + alloc((size_t)Bg * 512 * 512 * 4));
    float* xwA   = (float*)(ws + alloc((size_t)Bg * 2 * 64 * 768 * 4));
    float* xwB   = (float*)(ws + alloc((size_t)Bg * 2 * 64 * 768 * 4));
    float* whhT  = (float*)(ws + alloc(1966080ull * 4));
    float* hst   = (float*)(ws + alloc((size_t)Bg * 2 * 256 * 4));
    int*   perm  = (int*)  (ws + alloc(2048));
    int*   nchp  = perm + 256;
    float* xwbuf[2] = {xwA, xwB};

    sort_k<<<1, 256, 0, stream>>>(len, perm, nchp, Bg);
    prep_whhT_k<<<7680, 256, 0, stream>>>(Whh0, Whh, whhT);

    const int NR = 2 * Bg;                 // recur blocks (1 sample-dir each)
    const int NG = 12 * Bg;                // gemm blocks (6 col tiles x 2 dirs x Bg)

    for (int g0 = 0; g0 < 256; g0 += Bg) {
        const int gidx = g0 / Bg;
        input_proj_k<<<Bg * 512, 128, 0, stream>>>(x, len, perm, ln_g, ln_b,
                                                   w1, b1, w2, b2, h0, g0);
        float* bin = h0;
        float* bout = h1;
        for (int l = 0; l < 5; l++) {
            const int K = (l == 0) ? 128 : 512;
            const float* Wl  = (l == 0) ? Wih0 : (Wih + (size_t)(l - 1) * 2 * 768 * 512);
            const float* bil = (l == 0) ? bih0 : (bih + (size_t)(l - 1) * 1536);
            const float* whl = whhT + (size_t)l * 393216;
            const float* bhl = (l == 0) ? bhh0 : (bhh + (size_t)(l - 1) * 1536);
            for (int r = 0; r <= 8; r++) {
                round_k<<<NR + NG, 256, 0, stream>>>(
                    bin, K, Wl, bil, len, perm, nchp, gidx, g0, Bg,
                    xwbuf[r & 1], xwbuf[(r & 1) ^ 1],
                    whl, bhl, bout, hst, NR, r);
            }
            float* tmp = bin; bin = bout; bout = tmp;
        }
        pool_k<<<Bg, 256, 0, stream>>>(bin, len, perm, Wc, bc, out, g0);
    }
}